// Round 6
// baseline (400.322 us; speedup 1.0000x reference)
//
#include <hip/hip_runtime.h>
#include <hip/hip_fp16.h>

// Net_55439437857087: per-pixel MLP 2->8->4x(8x8)->3 over 16.7M pixels.
// History: R3/R4 512x512 table + bilinear (199us main). R5 quad 4MB:
// REGRESSED (L2 thrash + 96B/thread NT-store write amplification).
// R6 horiz-pair: halving gather REQUESTS -> only -3.5% (request-rate dead).
// R7 vertical-pair (1.125 lines/px): 151us (line-count is the lever).
// R9 A/B/C thirds: A(2x8B)=B(1x16B)=C(16B NT) -> per-instr term ~0,
// L1-allocate overhead ~0; scattered-line cost lives at/behind L2.
// Model: 151us = 48 streaming + ~81 line-service + ~22 residual. Pipes
// differ (HBM vs L2) yet costs ADD + VALU 15% + occ 78% => dependency-
// chain latency, starved on x-load MLP (2 NT loads in flight/wave).
// R10 (this round): software-pipelined 16px/thread. 4 groups of 4px per
// thread (grid-strided, lane-contiguous): all 8 NT x-loads issued first,
// then 2-deep gather pipeline (8 gathers in flight). Same 2MB table, same
// bit-identical 16B sampler, same 48B/group store pattern. ~96 VGPR ->
// occ ~62%, traded for 4x per-thread MLP.

#define EXP2F(x) __builtin_amdgcn_exp2f(x)
#define RCPF(x)  __builtin_amdgcn_rcpf(x)

#define G 512
#define GM1F 511.0f

typedef float vfloat4 __attribute__((ext_vector_type(4)));  // nontemporal-compatible
typedef unsigned int uv4 __attribute__((ext_vector_type(4), aligned(8)));

// ---- shared network evaluation (scale constants folded inline) ----
__device__ __forceinline__ void net_eval(
    float px, float py,
    const float* __restrict__ Win, const float* __restrict__ Wh,
    const float* __restrict__ Wout, float o[3])
{
    const float S  = 2.8853900817779268f;   // 2*log2(e)
    const float SO = -1.4426950408889634f;  // -log2(e)
    float h[8];
#pragma unroll
    for (int j = 0; j < 8; ++j) {
        float acc = __builtin_fmaf(px, Win[2 * j], py * Win[2 * j + 1]);
        h[j] = __builtin_fmaf(-2.0f, RCPF(EXP2F(S * acc) + 1.0f), 1.0f);
    }
#pragma unroll
    for (int L = 0; L < 4; ++L) {
        float nh[8];
#pragma unroll
        for (int j = 0; j < 8; ++j) {
            float acc = 0.0f;
#pragma unroll
            for (int k = 0; k < 8; ++k)
                acc = __builtin_fmaf(h[k], Wh[8 * j + k], acc);
            nh[j] = __builtin_fmaf(-2.0f, RCPF(EXP2F(S * acc) + 1.0f), 1.0f);
        }
#pragma unroll
        for (int j = 0; j < 8; ++j) h[j] = nh[j];
    }
#pragma unroll
    for (int c = 0; c < 3; ++c) {
        float acc = 0.0f;
#pragma unroll
        for (int k = 0; k < 8; ++k)
            acc = __builtin_fmaf(h[k], Wout[8 * c + k], acc);
        o[c] = RCPF(EXP2F(SO * acc) + 1.0f);
    }
}

// ================= build passes (unchanged) =================

__global__ __launch_bounds__(256) void build_tex_kernel(
    const float* __restrict__ Win, const float* __restrict__ Wh,
    const float* __restrict__ Wout, unsigned int* __restrict__ tex)
{
    int t = blockIdx.x * blockDim.x + threadIdx.x;
    if (t >= G * G) return;
    int i = t & (G - 1);
    int j = t >> 9;               // t / G
    const float inv = 1.0f / GM1F;
    float o[3];
    net_eval(i * inv, j * inv, Win, Wh, Wout, o);
    unsigned int r = (unsigned int)__builtin_rintf(o[0] * 2047.0f);
    unsigned int g = (unsigned int)__builtin_rintf(o[1] * 2047.0f);
    unsigned int b = (unsigned int)__builtin_rintf(o[2] * 1023.0f);
    tex[t] = r | (g << 11) | (b << 22);
}

// Entry (ix,iy): texel(ix,iy) in .x, texel(ix,iy+1) in .y  (vertical pair)
__global__ __launch_bounds__(256) void build_vpair_kernel(
    const unsigned int* __restrict__ tex, uint2* __restrict__ pair)
{
    int t = blockIdx.x * blockDim.x + threadIdx.x;
    if (t >= G * G) return;
    int ix = t & (G - 1);
    int iy = t >> 9;
    int iy1 = min(iy + 1, G - 1);
    uint2 q;
    q.x = tex[iy * G + ix];
    q.y = tex[iy1 * G + ix];
    pair[t] = q;
}

// ================= sampling primitives (bit-identical to R9-B) =========

__device__ __forceinline__ float3 unpack_raw(unsigned int v) {
    return make_float3((float)(v & 2047u),
                       (float)((v >> 11) & 2047u),
                       (float)(v >> 22));
}

__device__ __forceinline__ float3 lerp3(float3 a, float3 b, float t) {
    return make_float3(__builtin_fmaf(t, b.x - a.x, a.x),
                       __builtin_fmaf(t, b.y - a.y, a.y),
                       __builtin_fmaf(t, b.z - a.z, a.z));
}

__device__ __forceinline__ void issue_px(const uint2* __restrict__ tab,
    float px, float py, uv4& q, float& tx, float& ty)
{
    float fx = px * GM1F;
    float fy = py * GM1F;
    int ix = (int)fx;             // px in [0,1): ix <= 510, iy <= 510
    int iy = (int)fy;
    tx = fx - (float)ix;
    ty = fy - (float)iy;
    q = *reinterpret_cast<const uv4*>(tab + (iy << 9) + ix);
}

__device__ __forceinline__ float3 finish_px(uv4 q, float tx, float ty)
{
    // q.x=top(ix) q.y=bot(ix) q.z=top(ix+1) q.w=bot(ix+1)
    float3 c0 = lerp3(unpack_raw(q.x), unpack_raw(q.z), tx);
    float3 c1 = lerp3(unpack_raw(q.y), unpack_raw(q.w), tx);
    float3 r  = lerp3(c0, c1, ty);
    return make_float3(r.x * (1.0f / 2047.0f),
                       r.y * (1.0f / 2047.0f),
                       r.z * (1.0f / 1023.0f));
}

// group state: explicit members only (rule: no runtime-indexed reg arrays)
struct QGroup {
    uv4 q0, q1, q2, q3;
    float tx0, tx1, tx2, tx3;
    float ty0, ty1, ty2, ty3;
};

__device__ __forceinline__ void issue_group(const uint2* __restrict__ tab,
    vfloat4 xa, vfloat4 xb, QGroup& Q)
{
    issue_px(tab, xa.x, xa.y, Q.q0, Q.tx0, Q.ty0);
    issue_px(tab, xa.z, xa.w, Q.q1, Q.tx1, Q.ty1);
    issue_px(tab, xb.x, xb.y, Q.q2, Q.tx2, Q.ty2);
    issue_px(tab, xb.z, xb.w, Q.q3, Q.tx3, Q.ty3);
}

__device__ __forceinline__ void finish_group(const QGroup& Q,
    vfloat4* __restrict__ op, int g)
{
    float3 o0 = finish_px(Q.q0, Q.tx0, Q.ty0);
    float3 o1 = finish_px(Q.q1, Q.tx1, Q.ty1);
    float3 o2 = finish_px(Q.q2, Q.tx2, Q.ty2);
    float3 o3 = finish_px(Q.q3, Q.tx3, Q.ty3);
    vfloat4 s0 = {o0.x, o0.y, o0.z, o1.x};
    vfloat4 s1 = {o1.y, o1.z, o2.x, o2.y};
    vfloat4 s2 = {o2.z, o3.x, o3.y, o3.z};
    __builtin_nontemporal_store(s0, &op[3 * g + 0]);
    __builtin_nontemporal_store(s1, &op[3 * g + 1]);
    __builtin_nontemporal_store(s2, &op[3 * g + 2]);
}

// ---- R10 main pass: 16 px/thread, 4 grid-strided groups, 2-deep pipe ----
__global__ __launch_bounds__(256) void vpair_pipe_kernel(
    const float* __restrict__ x, const uint2* __restrict__ tab,
    float* __restrict__ out, int stride /* total threads = ngroups/4 */)
{
    int tid = blockIdx.x * blockDim.x + threadIdx.x;
    if (tid >= stride) return;
    const vfloat4* xv = reinterpret_cast<const vfloat4*>(x);
    vfloat4* op = reinterpret_cast<vfloat4*>(out);

    const int g0 = tid;
    const int g1 = tid + stride;
    const int g2 = tid + 2 * stride;
    const int g3 = tid + 3 * stride;

    // stage A: all 8 NT x-loads in flight
    vfloat4 xa0 = __builtin_nontemporal_load(&xv[2 * g0 + 0]);
    vfloat4 xb0 = __builtin_nontemporal_load(&xv[2 * g0 + 1]);
    vfloat4 xa1 = __builtin_nontemporal_load(&xv[2 * g1 + 0]);
    vfloat4 xb1 = __builtin_nontemporal_load(&xv[2 * g1 + 1]);
    vfloat4 xa2 = __builtin_nontemporal_load(&xv[2 * g2 + 0]);
    vfloat4 xb2 = __builtin_nontemporal_load(&xv[2 * g2 + 1]);
    vfloat4 xa3 = __builtin_nontemporal_load(&xv[2 * g3 + 0]);
    vfloat4 xb3 = __builtin_nontemporal_load(&xv[2 * g3 + 1]);

    // stage B: 2-deep gather pipeline (8 gathers in flight)
    QGroup QA, QB;
    issue_group(tab, xa0, xb0, QA);
    issue_group(tab, xa1, xb1, QB);
    finish_group(QA, op, g0);
    issue_group(tab, xa2, xb2, QA);
    finish_group(QB, op, g1);
    issue_group(tab, xa3, xb3, QB);
    finish_group(QA, op, g2);
    finish_group(QB, op, g3);
}

// ---- fallback main pass (any size): 4 px/thread, R9-B sampler ----
__global__ __launch_bounds__(256) void vpair_b_kernel(
    const float* __restrict__ x, const uint2* __restrict__ tab,
    float* __restrict__ out, int npix)
{
    int t = blockIdx.x * blockDim.x + threadIdx.x;
    if (t * 4 >= npix) return;
    const vfloat4* xv = reinterpret_cast<const vfloat4*>(x);
    vfloat4 xa = __builtin_nontemporal_load(&xv[2 * t + 0]);
    vfloat4 xb = __builtin_nontemporal_load(&xv[2 * t + 1]);
    QGroup Q;
    issue_group(tab, xa, xb, Q);
    finish_group(Q, reinterpret_cast<vfloat4*>(out), t);
}

// ================= fallback: direct evaluation, if ws too small =========

__global__ __launch_bounds__(256) void direct_kernel(
    const float* __restrict__ x,
    const float* __restrict__ Win, const float* __restrict__ Wh,
    const float* __restrict__ Wout, float* __restrict__ out, int npix)
{
    int t = blockIdx.x * blockDim.x + threadIdx.x;
    if (t * 4 >= npix) return;
    const float4* xv = reinterpret_cast<const float4*>(x);
    float4 xa = xv[2 * t + 0];
    float4 xb = xv[2 * t + 1];
    float o[4][3];
    net_eval(xa.x, xa.y, Win, Wh, Wout, o[0]);
    net_eval(xa.z, xa.w, Win, Wh, Wout, o[1]);
    net_eval(xb.x, xb.y, Win, Wh, Wout, o[2]);
    net_eval(xb.z, xb.w, Win, Wh, Wout, o[3]);
    float4 s0 = make_float4(o[0][0], o[0][1], o[0][2], o[1][0]);
    float4 s1 = make_float4(o[1][1], o[1][2], o[2][0], o[2][1]);
    float4 s2 = make_float4(o[2][2], o[3][0], o[3][1], o[3][2]);
    float4* op = reinterpret_cast<float4*>(out);
    op[3 * t + 0] = s0;
    op[3 * t + 1] = s1;
    op[3 * t + 2] = s2;
}

extern "C" void kernel_launch(void* const* d_in, const int* in_sizes, int n_in,
                              void* d_out, int out_size, void* d_ws, size_t ws_size,
                              hipStream_t stream) {
    const float* x    = (const float*)d_in[0];
    const float* Win  = (const float*)d_in[1];
    const float* Wh   = (const float*)d_in[2];
    const float* Wout = (const float*)d_in[3];
    float* out = (float*)d_out;

    const int npix = in_sizes[0] / 2;        // 16,777,216
    const int block = 256;

    const size_t pair_bytes = (size_t)G * G * sizeof(uint2);        // 2 MiB
    const size_t tex_bytes  = (size_t)G * G * sizeof(unsigned int); // 1 MiB

    if (ws_size >= pair_bytes + tex_bytes) {
        uint2* pair = (uint2*)d_ws;
        unsigned int* tex = (unsigned int*)((char*)d_ws + pair_bytes);
        build_tex_kernel<<<(G * G) / block, block, 0, stream>>>(Win, Wh, Wout, tex);
        build_vpair_kernel<<<(G * G) / block, block, 0, stream>>>(tex, pair);

        if (npix % (16 * block) == 0) {
            const int ngroups = npix / 4;
            const int stride = ngroups / 4;          // threads; 1,048,576
            vpair_pipe_kernel<<<stride / block, block, 0, stream>>>(
                x, pair, out, stride);
        } else {
            const int nthreads = npix / 4;
            vpair_b_kernel<<<(nthreads + block - 1) / block, block, 0, stream>>>(
                x, pair, out, npix);
        }
    } else {
        const int nthreads = npix / 4;
        direct_kernel<<<(nthreads + block - 1) / block, block, 0, stream>>>(
            x, Win, Wh, Wout, out, npix);
    }
}